// Round 9
// baseline (139.541 us; speedup 1.0000x reference)
//
#include <hip/hip_runtime.h>

// TotalVariationLoss: mean over (B,N,K) of squared distances to the K=8
// nearest neighbors (self excluded) of B*N 3D points. Only the SUM of each
// point's 8 smallest non-self d2 is needed.
//
// Round 7/8/9: med3 insertion (twice lost to infra, never measured).
// Inserting d into sorted h[0..7] is
//   r[k] = median(h[k-1], h[k], d)   (r[0] = min(h[0], d))
// -> 8 independent VALU ops per candidate, no sort network, no ballot.
// 12 ops/pair static vs ~25.75 effective in round 6 (issue-bound regime,
// confirmed by the round-6 occupancy experiment: 2x waves -> -5% time).

constexpr int B_    = 4;
constexpr int N_    = 8192;
constexpr int KNN   = 8;
constexpr int WAVES = 16;             // chunks per query group = waves/block
constexpr int BLOCK = WAVES * 64;     // 1024 threads
constexpr int CHUNK = N_ / WAVES;     // 512 candidates per wave

#define CE(a, b) { const float _lo = fminf(a, b); b = fmaxf(a, b); a = _lo; }

__global__ __launch_bounds__(256)
void prepack_kernel(const float* __restrict__ pts, float4* __restrict__ p4) {
    const int i = blockIdx.x * 256 + threadIdx.x;
    if (i < B_ * N_) {
        const float x = pts[i * 3 + 0], y = pts[i * 3 + 1], z = pts[i * 3 + 2];
        p4[i] = make_float4(x, y, z, fmaf(x, x, fmaf(y, y, z * z)));
    }
}

__global__ __launch_bounds__(BLOCK, 8)
void knn_tv_kernel(const float4* __restrict__ p4, float* __restrict__ out) {
    __shared__ float lists[(WAVES - 1) * 64][KNN + 1];   // 34.6 KiB

    const int tid   = threadIdx.x;
    const int lane  = tid & 63;
    const int w     = tid >> 6;               // wave id == chunk id
    const int g     = blockIdx.x;
    const int b     = g >> 7;                 // 128 query-groups per batch
    const int qbase = (g & 127) << 6;

    // force wave-uniform candidate base -> s_load scalar broadcast
    const int chunk_off = __builtin_amdgcn_readfirstlane(b * N_ + w * CHUNK);
    const float4* __restrict__ cnd = p4 + chunk_off;

    const float4 q  = p4[b * N_ + qbase + lane];         // coalesced 16B/lane
    const float qsq = q.w;
    const float m2x = -2.0f * q.x, m2y = -2.0f * q.y, m2z = -2.0f * q.z;

    float h[KNN];                              // ascending, h[7] = worst
#pragma unroll
    for (int k = 0; k < KNN; ++k) h[k] = 1e30f;

    // candidates [c0, c1) contain this wave's own queries (qsel 64-aligned)
    const int qsel = qbase - w * CHUNK;
    const bool own = (qsel >= 0) && (qsel < CHUNK);
    const int c0   = own ? qsel : CHUNK;
    const int c1   = own ? qsel + 64 : CHUNK;

    auto scan = [&](int lo, int hi, bool selfseg) {
#pragma unroll 4
        for (int i = lo; i < hi; ++i) {
            const float4 s = cnd[i];           // uniform -> scalar load
            float dd = fmaf(m2x, s.x, fmaf(m2y, s.y, fmaf(m2z, s.z, qsq + s.w)));
            if (selfseg) dd = (lane == i - qsel) ? 1e30f : dd;   // self -> no-op
            // branchless insert into sorted h: r[k] = med3(h[k-1], h[k], dd)
            const float n0 = fminf(h[0], dd);
            const float n1 = __builtin_amdgcn_fmed3f(h[0], h[1], dd);
            const float n2 = __builtin_amdgcn_fmed3f(h[1], h[2], dd);
            const float n3 = __builtin_amdgcn_fmed3f(h[2], h[3], dd);
            const float n4 = __builtin_amdgcn_fmed3f(h[3], h[4], dd);
            const float n5 = __builtin_amdgcn_fmed3f(h[4], h[5], dd);
            const float n6 = __builtin_amdgcn_fmed3f(h[5], h[6], dd);
            const float n7 = __builtin_amdgcn_fmed3f(h[6], h[7], dd);
            h[0] = n0; h[1] = n1; h[2] = n2; h[3] = n3;
            h[4] = n4; h[5] = n5; h[6] = n6; h[7] = n7;
        }
    };
    scan(0, c0, false);
    scan(c0, c1, true);                        // self handled here only
    scan(c1, CHUNK, false);

    // merge the 16 per-wave sorted lists (per query = per lane)
    if (w > 0) {
#pragma unroll
        for (int k = 0; k < KNN; ++k) lists[(w - 1) * 64 + lane][k] = h[k];
    }
    __syncthreads();
    if (w == 0) {
        for (int ww = 0; ww < WAVES - 1; ++ww) {
            float e[KNN];
#pragma unroll
            for (int k = 0; k < KNN; ++k) e[k] = lists[ww * 64 + lane][k];
            // top-8 of two sorted lists: elementwise min vs reversed -> bitonic
            float m0 = fminf(h[0], e[7]), m1 = fminf(h[1], e[6]);
            float m2 = fminf(h[2], e[5]), m3 = fminf(h[3], e[4]);
            float m4 = fminf(h[4], e[3]), m5 = fminf(h[5], e[2]);
            float m6 = fminf(h[6], e[1]), m7 = fminf(h[7], e[0]);
            CE(m0, m4) CE(m1, m5) CE(m2, m6) CE(m3, m7)
            CE(m0, m2) CE(m1, m3) CE(m4, m6) CE(m5, m7)
            CE(m0, m1) CE(m2, m3) CE(m4, m5) CE(m6, m7)
            h[0] = m0; h[1] = m1; h[2] = m2; h[3] = m3;
            h[4] = m4; h[5] = m5; h[6] = m6; h[7] = m7;
        }
        float qsum = 0.0f;
#pragma unroll
        for (int k = 0; k < KNN; ++k) qsum += h[k];
#pragma unroll
        for (int off = 32; off >= 1; off >>= 1) qsum += __shfl_xor(qsum, off, 64);
        if (lane == 0)
            atomicAdd(out, qsum * (1.0f / ((float)B_ * N_ * KNN)));
    }
}

extern "C" void kernel_launch(void* const* d_in, const int* in_sizes, int n_in,
                              void* d_out, int out_size, void* d_ws, size_t ws_size,
                              hipStream_t stream) {
    const float* pts = (const float*)d_in[0];
    float* out = (float*)d_out;
    float4* p4 = (float4*)d_ws;               // 4*8192*16 = 512 KiB scratch

    hipMemsetAsync(out, 0, (size_t)out_size * sizeof(float), stream);
    prepack_kernel<<<(B_ * N_ + 255) / 256, 256, 0, stream>>>(pts, p4);
    knn_tv_kernel<<<B_ * (N_ / 64), BLOCK, 0, stream>>>(p4, out);
}